// Round 1
// baseline (567.257 us; speedup 1.0000x reference)
//
#include <hip/hip_runtime.h>

#define TT 512
#define BB 1024
#define VV 96
#define LL 48
#define SS 97
#define NEG_INF (-1e30f)

// Stable 3-way logsumexp (alphas can be ~ -1e30, must stabilize).
__device__ __forceinline__ float lse3(float a, float b, float c) {
    float m = fmaxf(fmaxf(a, b), c);
    return m + __logf(__expf(a - m) + __expf(b - m) + __expf(c - m));
}

__global__ __launch_bounds__(64) void ctc_alpha_kernel(
        const int* __restrict__ labels,
        const float* __restrict__ yp,
        float* __restrict__ loss) {
    const int b = blockIdx.x;
    const int l = threadIdx.x;

    __shared__ int lab[LL];
    if (l < LL) lab[l] = labels[b * LL + l];
    __syncthreads();

    // Extended-label states owned by this lane: s0 = l, s1 = 64+l (valid l<33)
    const int s0 = l;
    const int s1 = 64 + l;
    const bool v1 = (s1 < SS);

    int i0 = s0 >> 1;                       // label index if s0 odd (<=31)
    int i1 = s1 >> 1; if (i1 > LL - 1) i1 = LL - 1;  // clamp (s1=96 -> unused)
    const int la0 = lab[i0];
    const int lp0 = lab[(i0 > 0) ? i0 - 1 : 0];
    const int la1 = lab[i1];
    const int lp1 = lab[(i1 > 0) ? i1 - 1 : 0];

    const int e0 = (s0 & 1) ? la0 : 0;                       // ext[s0]
    const int e1 = ((s1 & 1) && v1) ? la1 : 0;               // ext[s1]
    const bool skip0 = (s0 & 1) && (s0 >= 3) && (la0 != lp0);
    const bool skip1 = v1 && (s1 & 1) && (la1 != lp1);

    // Row loading: 96 floats as 48 float2; lanes 48..63 duplicate lane 47
    // (their contribution is masked out of the reduction).
    const bool act = (l < 48);
    const int cl = act ? l : 47;
    const float2* base2 = (const float2*)yp;
    const size_t rowStride2 = (size_t)BB * VV / 2;  // float2 per timestep
    const size_t bOff = (size_t)b * (VV / 2) + cl;

    // ---- t = 0 ----
    float2 x = base2[bOff];
    float se = act ? (__expf(x.x) + __expf(x.y)) : 0.f;
    #pragma unroll
    for (int m = 1; m < 64; m <<= 1) se += __shfl_xor(se, m);
    float lse = __logf(se);

    // emission gather: x[e] held by lane e>>1, component e&1
    float g0x = __shfl(x.x, e0 >> 1), g0y = __shfl(x.y, e0 >> 1);
    float em0 = ((e0 & 1) ? g0y : g0x) - lse;

    float A0 = (s0 < 2) ? em0 : NEG_INF;
    float A1 = NEG_INF;

    // software pipeline: prefetch rows t+1, t+2
    float2 r1 = base2[rowStride2 * 1 + bOff];
    float2 r2 = base2[rowStride2 * 2 + bOff];

    for (int t = 1; t < TT; ++t) {
        float2 cx = r1;
        r1 = r2;
        int tn = t + 2; if (tn > TT - 1) tn = TT - 1;
        r2 = base2[rowStride2 * (size_t)tn + bOff];

        // log-softmax denominator (unstabilized: logits are ~N(0,1), safe in fp32)
        float s = act ? (__expf(cx.x) + __expf(cx.y)) : 0.f;
        #pragma unroll
        for (int m = 1; m < 64; m <<= 1) s += __shfl_xor(s, m);
        float l2 = __logf(s);

        // emissions for both owned states
        float ga = __shfl(cx.x, e0 >> 1), gb = __shfl(cx.y, e0 >> 1);
        float emA = ((e0 & 1) ? gb : ga) - l2;
        float gc = __shfl(cx.x, e1 >> 1), gd = __shfl(cx.y, e1 >> 1);
        float emB = ((e1 & 1) ? gd : gc) - l2;

        // neighbor alphas via shuffles (stitch the s=63/64 boundary)
        float u1  = __shfl_up(A0, 1);
        float u2  = __shfl_up(A0, 2);
        float w1  = __shfl_up(A1, 1);
        float w2  = __shfl_up(A1, 2);
        float b63 = __shfl(A0, 63);
        float b62 = __shfl(A0, 62);

        float a1_0 = (l >= 1) ? u1 : NEG_INF;
        float a2_0 = skip0 ? u2 : NEG_INF;              // lanes 0..2: skip0=false
        float a1_1 = (l == 0) ? b63 : w1;
        float a2_1 = skip1 ? ((l == 0) ? b62 : ((l == 1) ? b63 : w2)) : NEG_INF;

        float nA0 = lse3(A0, a1_0, a2_0) + emA;
        float nA1 = lse3(A1, a1_1, a2_1) + emB;
        A0 = nA0;
        A1 = nA1;
    }

    // loss_b = -logaddexp(alpha[S-1], alpha[S-2]) ; s=96 -> lane 32 A1, s=95 -> lane 31 A1
    float aLast = __shfl(A1, 32);
    float aPrev = __shfl(A1, 31);
    if (l == 0) {
        float m = fmaxf(aLast, aPrev);
        loss[b] = -(m + __logf(__expf(aLast - m) + __expf(aPrev - m)));
    }
}

__global__ __launch_bounds__(256) void ctc_mean_kernel(
        const float* __restrict__ loss, float* __restrict__ out) {
    const int tid = threadIdx.x;
    float v = loss[tid] + loss[tid + 256] + loss[tid + 512] + loss[tid + 768];
    #pragma unroll
    for (int m = 1; m < 64; m <<= 1) v += __shfl_xor(v, m);
    __shared__ float part[4];
    if ((tid & 63) == 0) part[tid >> 6] = v;
    __syncthreads();
    if (tid == 0) out[0] = (part[0] + part[1] + part[2] + part[3]) * (1.0f / (float)BB);
}

extern "C" void kernel_launch(void* const* d_in, const int* in_sizes, int n_in,
                              void* d_out, int out_size, void* d_ws, size_t ws_size,
                              hipStream_t stream) {
    const int* y_true = (const int*)d_in[0];     // [B, L] int32
    const float* y_pred = (const float*)d_in[1]; // [T, B, V] float32
    float* out = (float*)d_out;                  // scalar
    float* lossbuf = (float*)d_ws;               // [B] per-example loss

    ctc_alpha_kernel<<<BB, 64, 0, stream>>>(y_true, y_pred, lossbuf);
    ctc_mean_kernel<<<1, 256, 0, stream>>>(lossbuf, out);
}